// Round 1
// baseline (81.609 us; speedup 1.0000x reference)
//
#include <hip/hip_runtime.h>
#include <math.h>

// ANFIS: B=8192, D=256, R=64, O=256, fp32.
// logit[b,r] = -sum_i (x_i-mu_ir)^2/(2 sig_ir^2); frs=exp; f=frs/(sum+1e-8);
// out = sum_r f_r (x@W_r + b_r).
//
// Sound skip bound (unchanged from previous session, now precomputed):
//   logit_r <= -pmin_r*(||x||-||mu_r||)^2,  pmin_r = min_i 0.5/sig_ir^2.
//   skip row iff for all r: pmin_r*(||x||-||mu_r||)^2 > 42  ( > -ln(SKIP_T*EPS)=41.45 )
//   <=> ||x|| outside [nmu_r - sqrt(42/pmin_r), nmu_r + sqrt(42/pmin_r)] for all r.
// If skipped, every f_r < 1e-10 and the fp32 reference itself underflows to
// exactly 0 (logits ~ N(-129,11)) -> write zeros.
//
// Restructure vs previous version: the per-rule intervals are computed ONCE by
// a 1-block stats kernel into d_ws (previously every one of 256 blocks re-read
// the full 128KB of mu/sig = 32MB aggregate L2 traffic, with 4 barrier-chained
// phases at 1 block/CU occupancy). The main kernel is now a barrier-free
// streaming kernel: one wave per row, 2048 blocks (8/CU), coalesced float4
// read of x (8.4MB) + float4 zero store of out (8.4MB) ~= pure BW floor.

constexpr int Bn = 8192, Dn = 256, Rn = 64, On = 256;
constexpr float EPS = 1e-8f;
constexpr float SKIP_T = 1e-10f;
constexpr float NEG_LOG_SKIP = 42.0f;   // > -ln(SKIP_T*EPS) = 41.45 (safety)

// ---------------------------------------------------------------------------
// Kernel 1: per-rule skip intervals on ||x||.  ws[r] = lo_r, ws[64+r] = hi_r.
// One block, 256 threads. Thread (ip, r4) covers i in [16ip,16ip+16), rules
// r4..r4+3, coalesced float4 rows of mu/sig.
// ---------------------------------------------------------------------------
__global__ __launch_bounds__(256) void anfis_stats(
    const float* __restrict__ mu, const float* __restrict__ sig,
    float* __restrict__ ws)
{
  __shared__ float smin[16 * Rn];   // per-phase min p partials
  __shared__ float ssum[16 * Rn];   // per-phase sum mu^2 partials

  const int tid = threadIdx.x;
  const int r4 = (tid & 15) << 2;
  const int ip = tid >> 4;
  float4 pmin4 = {1e30f, 1e30f, 1e30f, 1e30f};
  float4 msum4 = {0.f, 0.f, 0.f, 0.f};
#pragma unroll 4
  for (int k = 0; k < 16; ++k) {
    const int i = ip * 16 + k;
    float4 m = *reinterpret_cast<const float4*>(&mu [(size_t)i * Rn + r4]);
    float4 s = *reinterpret_cast<const float4*>(&sig[(size_t)i * Rn + r4]);
    float p0 = 0.5f / (s.x * s.x), p1 = 0.5f / (s.y * s.y);
    float p2 = 0.5f / (s.z * s.z), p3 = 0.5f / (s.w * s.w);
    pmin4.x = fminf(pmin4.x, p0); msum4.x = fmaf(m.x, m.x, msum4.x);
    pmin4.y = fminf(pmin4.y, p1); msum4.y = fmaf(m.y, m.y, msum4.y);
    pmin4.z = fminf(pmin4.z, p2); msum4.z = fmaf(m.z, m.z, msum4.z);
    pmin4.w = fminf(pmin4.w, p3); msum4.w = fmaf(m.w, m.w, msum4.w);
  }
  *reinterpret_cast<float4*>(&smin[ip * Rn + r4]) = pmin4;
  *reinterpret_cast<float4*>(&ssum[ip * Rn + r4]) = msum4;
  __syncthreads();

  if (tid < Rn) {
    float pm = 1e30f, nm = 0.f;
#pragma unroll
    for (int g = 0; g < 16; ++g) {
      pm = fminf(pm, smin[g * Rn + tid]);
      nm += ssum[g * Rn + tid];
    }
    const float nmu = sqrtf(nm);
    const float rad = sqrtf(NEG_LOG_SKIP / pm);
    ws[tid]      = nmu - rad;   // lo_r
    ws[Rn + tid] = nmu + rad;   // hi_r
  }
}

// ---------------------------------------------------------------------------
// Kernel 2: streaming row check. One wave per row, 4 waves/block, no barriers.
// ---------------------------------------------------------------------------
__global__ __launch_bounds__(256) void anfis_main(
    const float* __restrict__ x, const float* __restrict__ mu,
    const float* __restrict__ sig, const float* __restrict__ W,
    const float* __restrict__ bb, const float* __restrict__ ws,
    float* __restrict__ out)
{
  __shared__ float xs[4][Dn];   // fallback only (per-wave row buffer)
  __shared__ float fw[4][Rn];   // fallback only (per-wave memberships)

  const int tid  = threadIdx.x;
  const int lane = tid & 63;
  const int wid  = tid >> 6;
  const int row  = blockIdx.x * 4 + wid;

  // per-lane rule interval (lane == rule; 64 rules == 64 lanes)
  const float lo = ws[lane];
  const float hi = ws[Rn + lane];

  // coalesced 1KB row read; sum of squares
  const float4 v = *reinterpret_cast<const float4*>(&x[(size_t)row * Dn + (lane << 2)]);
  float ss = v.x * v.x;
  ss = fmaf(v.y, v.y, ss); ss = fmaf(v.z, v.z, ss); ss = fmaf(v.w, v.w, ss);
  ss += __shfl_xor(ss, 1);  ss += __shfl_xor(ss, 2);  ss += __shfl_xor(ss, 4);
  ss += __shfl_xor(ss, 8);  ss += __shfl_xor(ss, 16); ss += __shfl_xor(ss, 32);
  const float nx = sqrtf(ss);

  const int hit = (nx >= lo) & (nx <= hi);
  float* op = out + (size_t)row * On + (lane << 2);
  if (!__any(hit)) {
    // all 64 rule bounds < -42: reference underflows to exactly 0
    const float4 z = {0.f, 0.f, 0.f, 0.f};
    *reinterpret_cast<float4*>(op) = z;
    return;
  }

  // ---- exact path (statistically never taken; wave-local, no barriers) ----
  *reinterpret_cast<float4*>(&xs[wid][lane << 2]) = v;   // same-wave LDS: lgkmcnt only

  // lane = rule r: exact logit
  float acc = 0.f;
  for (int i = 0; i < Dn; ++i) {
    const float m = mu [(size_t)i * Rn + lane];
    const float s = sig[(size_t)i * Rn + lane];
    const float d = xs[wid][i] - m;
    acc = fmaf(d * d, 0.5f / (s * s), acc);
  }
  float frs = expf(-acc);   // + AMPLI (=0)

  float sum = frs, mx = frs;
#pragma unroll
  for (int off = 1; off < 64; off <<= 1) {
    sum += __shfl_xor(sum, off);
    mx = fmaxf(mx, __shfl_xor(mx, off));
  }
  const float inv = 1.f / (sum + EPS);

  if (mx * inv < SKIP_T) {
    const float4 z = {0.f, 0.f, 0.f, 0.f};
    *reinterpret_cast<float4*>(op) = z;
    return;
  }

  fw[wid][lane] = frs * inv;
  // each lane computes 4 outputs o = lane*4..lane*4+3 (coalesced W reads)
  float4 a = {0.f, 0.f, 0.f, 0.f};
  for (int r = 0; r < Rn; ++r) {
    const float fr = fw[wid][r];
    if (fr != 0.f) {
      const float* Wr = &W[(size_t)r * Dn * On];
      float4 dot = {0.f, 0.f, 0.f, 0.f};
      for (int i = 0; i < Dn; ++i) {
        const float4 w4 = *reinterpret_cast<const float4*>(&Wr[(size_t)i * On + (lane << 2)]);
        const float xi = xs[wid][i];
        dot.x = fmaf(xi, w4.x, dot.x);
        dot.y = fmaf(xi, w4.y, dot.y);
        dot.z = fmaf(xi, w4.z, dot.z);
        dot.w = fmaf(xi, w4.w, dot.w);
      }
      const float4 b4 = *reinterpret_cast<const float4*>(&bb[(size_t)r * On + (lane << 2)]);
      a.x = fmaf(fr, dot.x + b4.x, a.x);
      a.y = fmaf(fr, dot.y + b4.y, a.y);
      a.z = fmaf(fr, dot.z + b4.z, a.z);
      a.w = fmaf(fr, dot.w + b4.w, a.w);
    }
  }
  *reinterpret_cast<float4*>(op) = a;
}

extern "C" void kernel_launch(void* const* d_in, const int* in_sizes, int n_in,
                              void* d_out, int out_size, void* d_ws, size_t ws_size,
                              hipStream_t stream) {
  const float* x   = (const float*)d_in[0];
  const float* mu  = (const float*)d_in[1];
  const float* sig = (const float*)d_in[2];
  const float* W   = (const float*)d_in[3];
  const float* b   = (const float*)d_in[4];
  float* out = (float*)d_out;
  float* ws  = (float*)d_ws;

  anfis_stats<<<1, 256, 0, stream>>>(mu, sig, ws);
  anfis_main<<<Bn / 4, 256, 0, stream>>>(x, mu, sig, W, b, ws, out);
}